// Round 4
// baseline (644.875 us; speedup 1.0000x reference)
//
#include <hip/hip_runtime.h>

// ---------------------------------------------------------------------------
// QKGainAttention on MI355X (gfx950), round 4.
// Round 3's forced __launch_bounds__(256,4) capped total regs at 128/wave ->
// massive scratch spills (WRITE_SIZE 510MB, kernel spill-bound). Round 4 =
// round 3 structure with the bound relaxed to (256): S^T = K*Q^T MFMA,
// 2-shuffle softmax, 3-shfl P->B-frag transform (no Ps LDS), reg prefetch,
// qt pairing for CU load balance.
// ---------------------------------------------------------------------------

#define DEVINL __device__ __forceinline__

typedef unsigned short u16;
typedef __bf16 bf16x8 __attribute__((ext_vector_type(8)));
typedef float  f32x4  __attribute__((ext_vector_type(4)));
typedef short  short8 __attribute__((ext_vector_type(8)));
typedef u16    u16x4  __attribute__((ext_vector_type(4)));

static constexpr int T_  = 2048;
static constexpr int C_  = 2048;
static constexpr int TC3 = 6144;   // 3*C

DEVINL u16 f2bf(float f) {
  union { float f; unsigned u; } v; v.f = f;
  unsigned r = v.u + 0x7FFFu + ((v.u >> 16) & 1u);   // RNE
  return (u16)(r >> 16);
}
DEVINL float bf2f(u16 s) {
  union { unsigned u; float f; } v; v.u = ((unsigned)s) << 16;
  return v.f;
}
DEVINL bf16x8 ld8(const u16* p) {
  return __builtin_bit_cast(bf16x8, *(const short8*)p);
}
DEVINL f32x4 mfma16(bf16x8 a, bf16x8 b, f32x4 c) {
  return __builtin_amdgcn_mfma_f32_16x16x32_bf16(a, b, c, 0, 0, 0);
}
DEVINL void async_cp16(const u16* gp, u16* lp) {
  __builtin_amdgcn_global_load_lds(
      (const __attribute__((address_space(1))) void*)gp,
      (__attribute__((address_space(3))) void*)lp, 16, 0, 0);
}

// ---------------- dtype casts ----------------
__global__ __launch_bounds__(256) void k_cast_x(const float* __restrict__ in,
                                                u16* __restrict__ out) {
  long i = (long)(blockIdx.x * 256 + threadIdx.x) * 4;
  float4 v = *(const float4*)(in + i);
  u16x4 o; o.x = f2bf(v.x); o.y = f2bf(v.y); o.z = f2bf(v.z); o.w = f2bf(v.w);
  *(u16x4*)(out + i) = o;
}
__global__ __launch_bounds__(256) void k_cast_w(const int* __restrict__ in,
                                                u16* __restrict__ out) {
  long i = (long)(blockIdx.x * 256 + threadIdx.x) * 4;
  int4 v = *(const int4*)(in + i);
  u16x4 o; o.x = f2bf((float)v.x); o.y = f2bf((float)v.y);
  o.z = f2bf((float)v.z); o.w = f2bf((float)v.w);
  *(u16x4*)(out + i) = o;
}

// ---------------- GEMM: C[m,n] = (sum_k A[m,k]*Bt[n,k]) * scale[n] ----------
template<bool OUT_BF16>
__global__ __launch_bounds__(256) void k_gemm_bt(
    const u16* __restrict__ A, const u16* __restrict__ Bt,
    const float* __restrict__ scale, void* __restrict__ Cv,
    int N, long K) {
  __shared__ u16 As[128 * 32];
  __shared__ u16 Bs[128 * 32];
  const int tid  = threadIdx.x;
  const int wave = tid >> 6;
  const int lane = tid & 63;
  const int l15  = lane & 15;
  const int quad = lane >> 4;
  const int wm = (wave & 1) * 64;
  const int wn = (wave >> 1) * 64;
  const long bm = (long)blockIdx.y * 128;
  const long bn = (long)blockIdx.x * 128;

  f32x4 acc[4][4] = {};

  const int srow = lane >> 2;
  const int scol = (lane & 3) * 8;

  for (long k0 = 0; k0 < K; k0 += 32) {
#pragma unroll
    for (int i = 0; i < 2; ++i) {
      const int j = wave * 2 + i;
      const int row = j * 16 + srow;
      async_cp16(A  + (bm + row) * K + k0 + scol, &As[j * 512]);
      async_cp16(Bt + (bn + row) * K + k0 + scol, &Bs[j * 512]);
    }
    __syncthreads();
    bf16x8 af[4], bfr[4];
#pragma unroll
    for (int mi = 0; mi < 4; ++mi)
      af[mi] = ld8(&As[(wm + mi * 16 + l15) * 32 + quad * 8]);
#pragma unroll
    for (int ni = 0; ni < 4; ++ni)
      bfr[ni] = ld8(&Bs[(wn + ni * 16 + l15) * 32 + quad * 8]);
#pragma unroll
    for (int mi = 0; mi < 4; ++mi)
#pragma unroll
      for (int ni = 0; ni < 4; ++ni)
        acc[mi][ni] = mfma16(af[mi], bfr[ni], acc[mi][ni]);
    __syncthreads();
  }
#pragma unroll
  for (int ni = 0; ni < 4; ++ni) {
    const long col = bn + wn + ni * 16 + l15;
    const float sc = scale[col];
#pragma unroll
    for (int mi = 0; mi < 4; ++mi) {
      const long row0 = bm + wm + mi * 16 + quad * 4;
#pragma unroll
      for (int r = 0; r < 4; ++r) {
        float v = acc[mi][ni][r] * sc;
        if constexpr (OUT_BF16) ((u16*)Cv)[(row0 + r) * (long)N + col] = f2bf(v);
        else                    ((float*)Cv)[(row0 + r) * (long)N + col] = v;
      }
    }
  }
}

// ---------------- l2norm(q,k); fold qk_gain^2*log2e/sqrt(HD) into q ---------
__global__ __launch_bounds__(256) void k_norm_qk(u16* __restrict__ qkv,
                                                 const float* __restrict__ qk_gain) {
  const int token = blockIdx.x;
  const int wave = threadIdx.x >> 6, lane = threadIdx.x & 63;
  const float g = qk_gain[0];
  const float qmul = g * g * 1.44269504f * 0.08838834764f;
  u16* rowp = qkv + (long)token * TC3;
#pragma unroll
  for (int s = 0; s < 8; ++s) {
    const int seg = wave * 8 + s;
    const int isK = seg >> 4;
    const int h = seg & 15;
    u16* ptr = rowp + isK * C_ + h * 128 + lane * 2;
    unsigned pv = *(const unsigned*)ptr;
    float a = bf2f((u16)(pv & 0xffffu));
    float bb = bf2f((u16)(pv >> 16));
    float ss = a * a + bb * bb;
#pragma unroll
    for (int m = 1; m <= 32; m <<= 1) ss += __shfl_xor(ss, m);
    float denom = fmaxf(sqrtf(ss), 1e-12f);
    float f = (isK ? 1.0f : qmul) / denom;
    u16 o0 = f2bf(a * f), o1 = f2bf(bb * f);
    *(unsigned*)ptr = (unsigned)o0 | ((unsigned)o1 << 16);
  }
}

// ---------------- V transpose: qkv V block -> Vt_g[bz][h][d][t] -------------
__global__ __launch_bounds__(256) void k_vt(const u16* __restrict__ qkv,
                                            u16* __restrict__ vt) {
  const int t0 = blockIdx.x * 64;
  const int h = blockIdx.y, bz = blockIdx.z;
  const int t = threadIdx.x & 63;
  const int d0 = threadIdx.x >> 6;         // 0..3
  const long tokbase = (long)bz * T_;
  const u16* src = qkv + (tokbase + t0 + t) * (long)TC3 + 2 * C_ + h * 128;
  u16* dst = vt + ((long)(bz * 16 + h) * 128) * (long)T_ + t0 + t;
#pragma unroll
  for (int dd = 0; dd < 32; ++dd) {
    const int d = dd * 4 + d0;
    dst[(long)d * T_] = src[d];
  }
}

// ---------------- flash attention (causal), S^T formulation -----------------
__global__ __launch_bounds__(256) void k_attn(const u16* __restrict__ qkv,
                                              const u16* __restrict__ vtg,
                                              u16* __restrict__ y) {
  // qt pairing: co-resident blocks (y, y^8) get complementary strip lengths.
  const int qt = (blockIdx.y & 8) ? (31 - blockIdx.x) : blockIdx.x;
  const int h  = blockIdx.y;
  const int bz = blockIdx.z;
  const int tid = threadIdx.x, w = tid >> 6, lane = tid & 63;
  const int l15 = lane & 15, quad = lane >> 4;

  __shared__ u16 Ks[64 * 136];             // [key][d], pad 136
  __shared__ u16 Vt[128 * 72];             // [d][key], pad 72

  const long tokbase = (long)bz * T_;
  const int qbase = qt * 64 + w * 16;
  const u16* vbase = vtg + ((long)(bz * 16 + h) * 128) * (long)T_;

  // Q fragments (frag map lane&15=query, quad*8+j=d) in registers
  bf16x8 qf[4];
  {
    const u16* qp = qkv + (tokbase + qbase + l15) * TC3 + h * 128 + quad * 8;
#pragma unroll
    for (int kc = 0; kc < 4; ++kc)
      qf[kc] = ld8(qp + kc * 32);
  }

  f32x4 o[8] = {};                         // O^T: (d = db*16+quad*4+r, m=l15)
  float mrow = -1e30f, lrow = 0.f;         // per-query scalars (lane-resident)

  const int ksr = tid >> 4;                // K staging row (16 rows/pass)
  const int ksc = (tid & 15) * 8;
  const int vds = tid >> 3;                // Vt staging d (32 d/pass)
  const int vko = (tid & 7) * 8;

  // register prefetch buffers
  int4 kpre[4], vpre[4];
  {
    const int ktb = 0;
#pragma unroll
    for (int rr = 0; rr < 4; ++rr)
      kpre[rr] = *(const int4*)(qkv + (tokbase + ktb + rr * 16 + ksr) * TC3 + C_ + h * 128 + ksc);
#pragma unroll
    for (int ii = 0; ii < 4; ++ii)
      vpre[ii] = *(const int4*)(vbase + (long)(ii * 32 + vds) * T_ + ktb + vko);
  }

  for (int kt = 0; kt <= qt; ++kt) {
    const int ktb = kt * 64;
    // --- write prefetched tile to LDS ---
#pragma unroll
    for (int rr = 0; rr < 4; ++rr)
      *(int4*)&Ks[(rr * 16 + ksr) * 136 + ksc] = kpre[rr];
#pragma unroll
    for (int ii = 0; ii < 4; ++ii)
      *(int4*)&Vt[(ii * 32 + vds) * 72 + vko] = vpre[ii];
    __syncthreads();
    // --- prefetch next tile (overlaps compute below) ---
    if (kt < qt) {
      const int nb = ktb + 64;
#pragma unroll
      for (int rr = 0; rr < 4; ++rr)
        kpre[rr] = *(const int4*)(qkv + (tokbase + nb + rr * 16 + ksr) * TC3 + C_ + h * 128 + ksc);
#pragma unroll
      for (int ii = 0; ii < 4; ++ii)
        vpre[ii] = *(const int4*)(vbase + (long)(ii * 32 + vds) * T_ + nb + vko);
    }

    const int nvalid = min(64, qbase + 16 - ktb);
    const int nkb = (nvalid + 15) >> 4;
    const int nkc = (nvalid + 31) >> 5;
    const bool diag = (kt == qt);

    // --- S^T = K·Q^T: C-layout (key=quad*4+r, query=l15) ---
    f32x4 sb[4] = {};                      // invalid kb stay 0 (PV-safe)
#pragma unroll
    for (int kb = 0; kb < 4; ++kb) {
      if (kb < nkb) {
        f32x4 acc = {0.f, 0.f, 0.f, 0.f};
#pragma unroll
        for (int kc = 0; kc < 4; ++kc) {
          bf16x8 kf = ld8(&Ks[(kb * 16 + l15) * 136 + kc * 32 + quad * 8]);
          acc = mfma16(kf, qf[kc], acc);
        }
        if (diag) {
          const int keyb = ktb + kb * 16 + quad * 4;
#pragma unroll
          for (int r = 0; r < 4; ++r)
            if (keyb + r > qbase + l15) acc[r] = -1e30f;
        }
        sb[kb] = acc;
      }
    }
    // --- online softmax: query on l15, reduce over regs + 2 shuffles ---
    float mx = -1e30f;
#pragma unroll
    for (int kb = 0; kb < 4; ++kb)
      if (kb < nkb)
#pragma unroll
        for (int r = 0; r < 4; ++r) mx = fmaxf(mx, sb[kb][r]);
    mx = fmaxf(mx, __shfl_xor(mx, 16));
    mx = fmaxf(mx, __shfl_xor(mx, 32));
    const float mnew = fmaxf(mrow, mx);
    const float alpha = __builtin_amdgcn_exp2f(mrow - mnew);
    mrow = mnew;
    float rs = 0.f;
#pragma unroll
    for (int kb = 0; kb < 4; ++kb)
      if (kb < nkb)
#pragma unroll
        for (int r = 0; r < 4; ++r) {
          float p = __builtin_amdgcn_exp2f(sb[kb][r] - mnew);
          sb[kb][r] = p;
          rs += p;
        }
    rs += __shfl_xor(rs, 16);
    rs += __shfl_xor(rs, 32);
    lrow = lrow * alpha + rs;
#pragma unroll
    for (int db = 0; db < 8; ++db)
#pragma unroll
      for (int r = 0; r < 4; ++r) o[db][r] *= alpha;

    // --- P^T C-frags -> B-frag via quad exchange; O^T += V^T P^T ---
#pragma unroll
    for (int kc2 = 0; kc2 < 2; ++kc2) {
      if (kc2 < nkc) {
        f32x4 e0 = sb[kc2 * 2], e1 = sb[kc2 * 2 + 1];
        f32x4 Y, Z;
#pragma unroll
        for (int i = 0; i < 4; ++i) {
          Y[i] = (quad & 2) ? e1[i] : e0[i];
          Z[i] = (quad & 2) ? e0[i] : e1[i];
        }
        f32x4 r16, r32, r48;
#pragma unroll
        for (int i = 0; i < 4; ++i) {
          r16[i] = __shfl_xor(Y[i], 16);
          r32[i] = __shfl_xor(Z[i], 32);
          r48[i] = __shfl_xor(Z[i], 48);
        }
        // lo: source quad (q&1)*2, regs j=0..3 ; hi: source quad (q&1)*2+1
        f32x4 lo, hi;
#pragma unroll
        for (int i = 0; i < 4; ++i) {
          lo[i] = (quad == 0) ? Y[i] : (quad == 1) ? r48[i] : (quad == 2) ? r32[i] : r16[i];
          hi[i] = (quad == 0) ? r16[i] : (quad == 1) ? r32[i] : (quad == 2) ? r48[i] : Y[i];
        }
        bf16x8 pb;
#pragma unroll
        for (int i = 0; i < 4; ++i) {
          pb[i]     = (__bf16)lo[i];
          pb[i + 4] = (__bf16)hi[i];
        }
#pragma unroll
        for (int db = 0; db < 8; ++db) {
          bf16x8 vf = ld8(&Vt[(db * 16 + l15) * 72 + kc2 * 32 + quad * 8]);
          o[db] = mfma16(vf, pb, o[db]);
        }
      }
    }
    __syncthreads();
  }
  // --- epilogue: O^T lane holds (d=db*16+quad*4+r, m=l15); y[m][d] ---
  const float inv_l = 1.0f / lrow;
  u16* yp = y + (tokbase + qbase + l15) * (long)C_ + h * 128 + quad * 4;
#pragma unroll
  for (int db = 0; db < 8; ++db) {
    u16x4 pk;
#pragma unroll
    for (int r = 0; r < 4; ++r) pk[r] = f2bf(o[db][r] * inv_l);
    *(u16x4*)(yp + db * 16) = pk;
  }
}

// ---------------------------------------------------------------------------
extern "C" void kernel_launch(void* const* d_in, const int* in_sizes, int n_in,
                              void* d_out, int out_size, void* d_ws, size_t ws_size,
                              hipStream_t stream) {
  const float* x    = (const float*)d_in[0];
  const int*   aw   = (const int*)d_in[1];
  const float* asc  = (const float*)d_in[2];
  const int*   pw   = (const int*)d_in[3];
  const float* psc  = (const float*)d_in[4];
  const float* gain = (const float*)d_in[5];

  char* ws = (char*)d_ws;
  u16* xb  = (u16*)(ws);                         // 16.78 MB (reused as Vt_g)
  u16* wab = (u16*)(ws + 16777216UL);
  u16* wpb = (u16*)(ws + 41943040UL);
  u16* qkv = (u16*)(ws + 50331648UL);
  u16* yb  = (u16*)(ws + 100663296UL);
  u16* vtg = xb;                                 // x_bf16 dead after QKV GEMM

  k_cast_x<<<8192, 256, 0, stream>>>(x, xb);
  k_cast_w<<<12288, 256, 0, stream>>>(aw, wab);
  k_cast_w<<<4096, 256, 0, stream>>>(pw, wpb);
  k_gemm_bt<true><<<dim3(48, 32), 256, 0, stream>>>(xb, wab, asc, qkv, TC3, (long)C_);
  k_norm_qk<<<4096, 256, 0, stream>>>(qkv, gain);
  k_vt<<<dim3(32, 16, 2), 256, 0, stream>>>(qkv, vtg);
  k_attn<<<dim3(32, 16, 2), 256, 0, stream>>>(qkv, vtg, yb);
  k_gemm_bt<false><<<dim3(16, 32), 256, 0, stream>>>(yb, wpb, psc, (float*)d_out, C_, (long)C_);
}

// Round 5
// 567.723 us; speedup vs baseline: 1.1359x; 1.1359x over previous
//
#include <hip/hip_runtime.h>

// ---------------------------------------------------------------------------
// QKGainAttention on MI355X (gfx950), round 5.
// Root cause found for rounds 3-4 spills: the backend derives its VGPR budget
// from LDS-allowed occupancy. 35.8KB LDS -> 4 blocks/CU -> 128-reg cap ->
// spill (WRITE_SIZE 479MB). Fix: __launch_bounds__(256,3) -> 168-reg budget
// (kernel needs ~140). Structure unchanged from round 3/4: S^T = K*Q^T MFMA,
// 2-shuffle softmax, 3-shfl P->B-frag transform, reg prefetch, qt pairing.
// ---------------------------------------------------------------------------

#define DEVINL __device__ __forceinline__

typedef unsigned short u16;
typedef __bf16 bf16x8 __attribute__((ext_vector_type(8)));
typedef float  f32x4  __attribute__((ext_vector_type(4)));
typedef short  short8 __attribute__((ext_vector_type(8)));
typedef u16    u16x4  __attribute__((ext_vector_type(4)));

static constexpr int T_  = 2048;
static constexpr int C_  = 2048;
static constexpr int TC3 = 6144;   // 3*C

DEVINL u16 f2bf(float f) {
  union { float f; unsigned u; } v; v.f = f;
  unsigned r = v.u + 0x7FFFu + ((v.u >> 16) & 1u);   // RNE
  return (u16)(r >> 16);
}
DEVINL float bf2f(u16 s) {
  union { unsigned u; float f; } v; v.u = ((unsigned)s) << 16;
  return v.f;
}
DEVINL bf16x8 ld8(const u16* p) {
  return __builtin_bit_cast(bf16x8, *(const short8*)p);
}
DEVINL f32x4 mfma16(bf16x8 a, bf16x8 b, f32x4 c) {
  return __builtin_amdgcn_mfma_f32_16x16x32_bf16(a, b, c, 0, 0, 0);
}
DEVINL void async_cp16(const u16* gp, u16* lp) {
  __builtin_amdgcn_global_load_lds(
      (const __attribute__((address_space(1))) void*)gp,
      (__attribute__((address_space(3))) void*)lp, 16, 0, 0);
}

// ---------------- dtype casts ----------------
__global__ __launch_bounds__(256) void k_cast_x(const float* __restrict__ in,
                                                u16* __restrict__ out) {
  long i = (long)(blockIdx.x * 256 + threadIdx.x) * 4;
  float4 v = *(const float4*)(in + i);
  u16x4 o; o.x = f2bf(v.x); o.y = f2bf(v.y); o.z = f2bf(v.z); o.w = f2bf(v.w);
  *(u16x4*)(out + i) = o;
}
__global__ __launch_bounds__(256) void k_cast_w(const int* __restrict__ in,
                                                u16* __restrict__ out) {
  long i = (long)(blockIdx.x * 256 + threadIdx.x) * 4;
  int4 v = *(const int4*)(in + i);
  u16x4 o; o.x = f2bf((float)v.x); o.y = f2bf((float)v.y);
  o.z = f2bf((float)v.z); o.w = f2bf((float)v.w);
  *(u16x4*)(out + i) = o;
}

// ---------------- GEMM: C[m,n] = (sum_k A[m,k]*Bt[n,k]) * scale[n] ----------
template<bool OUT_BF16>
__global__ __launch_bounds__(256) void k_gemm_bt(
    const u16* __restrict__ A, const u16* __restrict__ Bt,
    const float* __restrict__ scale, void* __restrict__ Cv,
    int N, long K) {
  __shared__ u16 As[128 * 32];
  __shared__ u16 Bs[128 * 32];
  const int tid  = threadIdx.x;
  const int wave = tid >> 6;
  const int lane = tid & 63;
  const int l15  = lane & 15;
  const int quad = lane >> 4;
  const int wm = (wave & 1) * 64;
  const int wn = (wave >> 1) * 64;
  const long bm = (long)blockIdx.y * 128;
  const long bn = (long)blockIdx.x * 128;

  f32x4 acc[4][4] = {};

  const int srow = lane >> 2;
  const int scol = (lane & 3) * 8;

  for (long k0 = 0; k0 < K; k0 += 32) {
#pragma unroll
    for (int i = 0; i < 2; ++i) {
      const int j = wave * 2 + i;
      const int row = j * 16 + srow;
      async_cp16(A  + (bm + row) * K + k0 + scol, &As[j * 512]);
      async_cp16(Bt + (bn + row) * K + k0 + scol, &Bs[j * 512]);
    }
    __syncthreads();
    bf16x8 af[4], bfr[4];
#pragma unroll
    for (int mi = 0; mi < 4; ++mi)
      af[mi] = ld8(&As[(wm + mi * 16 + l15) * 32 + quad * 8]);
#pragma unroll
    for (int ni = 0; ni < 4; ++ni)
      bfr[ni] = ld8(&Bs[(wn + ni * 16 + l15) * 32 + quad * 8]);
#pragma unroll
    for (int mi = 0; mi < 4; ++mi)
#pragma unroll
      for (int ni = 0; ni < 4; ++ni)
        acc[mi][ni] = mfma16(af[mi], bfr[ni], acc[mi][ni]);
    __syncthreads();
  }
#pragma unroll
  for (int ni = 0; ni < 4; ++ni) {
    const long col = bn + wn + ni * 16 + l15;
    const float sc = scale[col];
#pragma unroll
    for (int mi = 0; mi < 4; ++mi) {
      const long row0 = bm + wm + mi * 16 + quad * 4;
#pragma unroll
      for (int r = 0; r < 4; ++r) {
        float v = acc[mi][ni][r] * sc;
        if constexpr (OUT_BF16) ((u16*)Cv)[(row0 + r) * (long)N + col] = f2bf(v);
        else                    ((float*)Cv)[(row0 + r) * (long)N + col] = v;
      }
    }
  }
}

// ---------------- l2norm(q,k); fold qk_gain^2*log2e/sqrt(HD) into q ---------
__global__ __launch_bounds__(256) void k_norm_qk(u16* __restrict__ qkv,
                                                 const float* __restrict__ qk_gain) {
  const int token = blockIdx.x;
  const int wave = threadIdx.x >> 6, lane = threadIdx.x & 63;
  const float g = qk_gain[0];
  const float qmul = g * g * 1.44269504f * 0.08838834764f;
  u16* rowp = qkv + (long)token * TC3;
#pragma unroll
  for (int s = 0; s < 8; ++s) {
    const int seg = wave * 8 + s;
    const int isK = seg >> 4;
    const int h = seg & 15;
    u16* ptr = rowp + isK * C_ + h * 128 + lane * 2;
    unsigned pv = *(const unsigned*)ptr;
    float a = bf2f((u16)(pv & 0xffffu));
    float bb = bf2f((u16)(pv >> 16));
    float ss = a * a + bb * bb;
#pragma unroll
    for (int m = 1; m <= 32; m <<= 1) ss += __shfl_xor(ss, m);
    float denom = fmaxf(sqrtf(ss), 1e-12f);
    float f = (isK ? 1.0f : qmul) / denom;
    u16 o0 = f2bf(a * f), o1 = f2bf(bb * f);
    *(unsigned*)ptr = (unsigned)o0 | ((unsigned)o1 << 16);
  }
}

// ---------------- V transpose: qkv V block -> Vt_g[bz][h][d][t] -------------
__global__ __launch_bounds__(256) void k_vt(const u16* __restrict__ qkv,
                                            u16* __restrict__ vt) {
  const int t0 = blockIdx.x * 64;
  const int h = blockIdx.y, bz = blockIdx.z;
  const int t = threadIdx.x & 63;
  const int d0 = threadIdx.x >> 6;         // 0..3
  const long tokbase = (long)bz * T_;
  const u16* src = qkv + (tokbase + t0 + t) * (long)TC3 + 2 * C_ + h * 128;
  u16* dst = vt + ((long)(bz * 16 + h) * 128) * (long)T_ + t0 + t;
#pragma unroll
  for (int dd = 0; dd < 32; ++dd) {
    const int d = dd * 4 + d0;
    dst[(long)d * T_] = src[d];
  }
}

// ---------------- flash attention (causal), S^T formulation -----------------
__global__ __launch_bounds__(256, 3) void k_attn(const u16* __restrict__ qkv,
                                                 const u16* __restrict__ vtg,
                                                 u16* __restrict__ y) {
  // qt pairing: co-resident blocks (y, y^8) get complementary strip lengths.
  const int qt = (blockIdx.y & 8) ? (31 - blockIdx.x) : blockIdx.x;
  const int h  = blockIdx.y;
  const int bz = blockIdx.z;
  const int tid = threadIdx.x, w = tid >> 6, lane = tid & 63;
  const int l15 = lane & 15, quad = lane >> 4;

  __shared__ u16 Ks[64 * 136];             // [key][d], pad 136
  __shared__ u16 Vt[128 * 72];             // [d][key], pad 72

  const long tokbase = (long)bz * T_;
  const int qbase = qt * 64 + w * 16;
  const u16* vbase = vtg + ((long)(bz * 16 + h) * 128) * (long)T_;

  // Q fragments (frag map lane&15=query, quad*8+j=d) in registers
  bf16x8 qf[4];
  {
    const u16* qp = qkv + (tokbase + qbase + l15) * TC3 + h * 128 + quad * 8;
#pragma unroll
    for (int kc = 0; kc < 4; ++kc)
      qf[kc] = ld8(qp + kc * 32);
  }

  f32x4 o[8] = {};                         // O^T: (d = db*16+quad*4+r, m=l15)
  float mrow = -1e30f, lrow = 0.f;         // per-query scalars (lane-resident)

  const int ksr = tid >> 4;                // K staging row (16 rows/pass)
  const int ksc = (tid & 15) * 8;
  const int vds = tid >> 3;                // Vt staging d (32 d/pass)
  const int vko = (tid & 7) * 8;

  // register prefetch buffers
  int4 kpre[4], vpre[4];
  {
    const int ktb = 0;
#pragma unroll
    for (int rr = 0; rr < 4; ++rr)
      kpre[rr] = *(const int4*)(qkv + (tokbase + ktb + rr * 16 + ksr) * TC3 + C_ + h * 128 + ksc);
#pragma unroll
    for (int ii = 0; ii < 4; ++ii)
      vpre[ii] = *(const int4*)(vbase + (long)(ii * 32 + vds) * T_ + ktb + vko);
  }

  for (int kt = 0; kt <= qt; ++kt) {
    const int ktb = kt * 64;
    // --- write prefetched tile to LDS ---
#pragma unroll
    for (int rr = 0; rr < 4; ++rr)
      *(int4*)&Ks[(rr * 16 + ksr) * 136 + ksc] = kpre[rr];
#pragma unroll
    for (int ii = 0; ii < 4; ++ii)
      *(int4*)&Vt[(ii * 32 + vds) * 72 + vko] = vpre[ii];
    __syncthreads();
    // --- prefetch next tile (overlaps compute below) ---
    if (kt < qt) {
      const int nb = ktb + 64;
#pragma unroll
      for (int rr = 0; rr < 4; ++rr)
        kpre[rr] = *(const int4*)(qkv + (tokbase + nb + rr * 16 + ksr) * TC3 + C_ + h * 128 + ksc);
#pragma unroll
      for (int ii = 0; ii < 4; ++ii)
        vpre[ii] = *(const int4*)(vbase + (long)(ii * 32 + vds) * T_ + nb + vko);
    }

    const int nvalid = min(64, qbase + 16 - ktb);
    const int nkb = (nvalid + 15) >> 4;
    const int nkc = (nvalid + 31) >> 5;
    const bool diag = (kt == qt);

    // --- S^T = K·Q^T: C-layout (key=quad*4+r, query=l15) ---
    f32x4 sb[4] = {};                      // invalid kb stay 0 (PV-safe)
#pragma unroll
    for (int kb = 0; kb < 4; ++kb) {
      if (kb < nkb) {
        f32x4 acc = {0.f, 0.f, 0.f, 0.f};
#pragma unroll
        for (int kc = 0; kc < 4; ++kc) {
          bf16x8 kf = ld8(&Ks[(kb * 16 + l15) * 136 + kc * 32 + quad * 8]);
          acc = mfma16(kf, qf[kc], acc);
        }
        if (diag) {
          const int keyb = ktb + kb * 16 + quad * 4;
#pragma unroll
          for (int r = 0; r < 4; ++r)
            if (keyb + r > qbase + l15) acc[r] = -1e30f;
        }
        sb[kb] = acc;
      }
    }
    // --- online softmax: query on l15, reduce over regs + 2 shuffles ---
    float mx = -1e30f;
#pragma unroll
    for (int kb = 0; kb < 4; ++kb)
      if (kb < nkb)
#pragma unroll
        for (int r = 0; r < 4; ++r) mx = fmaxf(mx, sb[kb][r]);
    mx = fmaxf(mx, __shfl_xor(mx, 16));
    mx = fmaxf(mx, __shfl_xor(mx, 32));
    const float mnew = fmaxf(mrow, mx);
    const float alpha = __builtin_amdgcn_exp2f(mrow - mnew);
    mrow = mnew;
    float rs = 0.f;
#pragma unroll
    for (int kb = 0; kb < 4; ++kb)
      if (kb < nkb)
#pragma unroll
        for (int r = 0; r < 4; ++r) {
          float p = __builtin_amdgcn_exp2f(sb[kb][r] - mnew);
          sb[kb][r] = p;
          rs += p;
        }
    rs += __shfl_xor(rs, 16);
    rs += __shfl_xor(rs, 32);
    lrow = lrow * alpha + rs;
#pragma unroll
    for (int db = 0; db < 8; ++db)
#pragma unroll
      for (int r = 0; r < 4; ++r) o[db][r] *= alpha;

    // --- P^T C-frags -> B-frag via quad exchange; O^T += V^T P^T ---
#pragma unroll
    for (int kc2 = 0; kc2 < 2; ++kc2) {
      if (kc2 < nkc) {
        f32x4 e0 = sb[kc2 * 2], e1 = sb[kc2 * 2 + 1];
        f32x4 Y, Z;
#pragma unroll
        for (int i = 0; i < 4; ++i) {
          Y[i] = (quad & 2) ? e1[i] : e0[i];
          Z[i] = (quad & 2) ? e0[i] : e1[i];
        }
        f32x4 r16, r32, r48;
#pragma unroll
        for (int i = 0; i < 4; ++i) {
          r16[i] = __shfl_xor(Y[i], 16);
          r32[i] = __shfl_xor(Z[i], 32);
          r48[i] = __shfl_xor(Z[i], 48);
        }
        // lo: source quad (q&1)*2, regs j=0..3 ; hi: source quad (q&1)*2+1
        f32x4 lo, hi;
#pragma unroll
        for (int i = 0; i < 4; ++i) {
          lo[i] = (quad == 0) ? Y[i] : (quad == 1) ? r48[i] : (quad == 2) ? r32[i] : r16[i];
          hi[i] = (quad == 0) ? r16[i] : (quad == 1) ? r32[i] : (quad == 2) ? r48[i] : Y[i];
        }
        bf16x8 pb;
#pragma unroll
        for (int i = 0; i < 4; ++i) {
          pb[i]     = (__bf16)lo[i];
          pb[i + 4] = (__bf16)hi[i];
        }
#pragma unroll
        for (int db = 0; db < 8; ++db) {
          bf16x8 vf = ld8(&Vt[(db * 16 + l15) * 72 + kc2 * 32 + quad * 8]);
          o[db] = mfma16(vf, pb, o[db]);
        }
      }
    }
    __syncthreads();
  }
  // --- epilogue: O^T lane holds (d=db*16+quad*4+r, m=l15); y[m][d] ---
  const float inv_l = 1.0f / lrow;
  u16* yp = y + (tokbase + qbase + l15) * (long)C_ + h * 128 + quad * 4;
#pragma unroll
  for (int db = 0; db < 8; ++db) {
    u16x4 pk;
#pragma unroll
    for (int r = 0; r < 4; ++r) pk[r] = f2bf(o[db][r] * inv_l);
    *(u16x4*)(yp + db * 16) = pk;
  }
}

// ---------------------------------------------------------------------------
extern "C" void kernel_launch(void* const* d_in, const int* in_sizes, int n_in,
                              void* d_out, int out_size, void* d_ws, size_t ws_size,
                              hipStream_t stream) {
  const float* x    = (const float*)d_in[0];
  const int*   aw   = (const int*)d_in[1];
  const float* asc  = (const float*)d_in[2];
  const int*   pw   = (const int*)d_in[3];
  const float* psc  = (const float*)d_in[4];
  const float* gain = (const float*)d_in[5];

  char* ws = (char*)d_ws;
  u16* xb  = (u16*)(ws);                         // 16.78 MB (reused as Vt_g)
  u16* wab = (u16*)(ws + 16777216UL);
  u16* wpb = (u16*)(ws + 41943040UL);
  u16* qkv = (u16*)(ws + 50331648UL);
  u16* yb  = (u16*)(ws + 100663296UL);
  u16* vtg = xb;                                 // x_bf16 dead after QKV GEMM

  k_cast_x<<<8192, 256, 0, stream>>>(x, xb);
  k_cast_w<<<12288, 256, 0, stream>>>(aw, wab);
  k_cast_w<<<4096, 256, 0, stream>>>(pw, wpb);
  k_gemm_bt<true><<<dim3(48, 32), 256, 0, stream>>>(xb, wab, asc, qkv, TC3, (long)C_);
  k_norm_qk<<<4096, 256, 0, stream>>>(qkv, gain);
  k_vt<<<dim3(32, 16, 2), 256, 0, stream>>>(qkv, vtg);
  k_attn<<<dim3(32, 16, 2), 256, 0, stream>>>(qkv, vtg, yb);
  k_gemm_bt<false><<<dim3(16, 32), 256, 0, stream>>>(yb, wpb, psc, (float*)d_out, C_, (long)C_);
}

// Round 6
// 554.926 us; speedup vs baseline: 1.1621x; 1.0231x over previous
//
#include <hip/hip_runtime.h>

// ---------------------------------------------------------------------------
// QKGainAttention on MI355X (gfx950), round 6.
// R3-R5 postmortem: allocator targets LDS-derived occupancy (35.8KB -> 4
// blocks/CU -> 128-reg budget) and SPILLS to hold it; launch_bounds' 2nd arg
// only lowers the cap, never raises the target. Fix: make the kernel fit 128
// regs -- drop kpre/vpre reg prefetch (-32 VGPR), stage K/V via async
// global_load_lds (no VGPR round-trip), XOR-swizzled unpadded LDS tiles
// (global_load_lds needs contiguous lane*16B dest; swizzle kills bank
// conflicts instead of padding). LDS 33.25KB -> exactly 4 blocks/CU.
// ---------------------------------------------------------------------------

#define DEVINL __device__ __forceinline__

typedef unsigned short u16;
typedef __bf16 bf16x8 __attribute__((ext_vector_type(8)));
typedef float  f32x4  __attribute__((ext_vector_type(4)));
typedef short  short8 __attribute__((ext_vector_type(8)));
typedef u16    u16x4  __attribute__((ext_vector_type(4)));

static constexpr int T_  = 2048;
static constexpr int C_  = 2048;
static constexpr int TC3 = 6144;   // 3*C

DEVINL u16 f2bf(float f) {
  union { float f; unsigned u; } v; v.f = f;
  unsigned r = v.u + 0x7FFFu + ((v.u >> 16) & 1u);   // RNE
  return (u16)(r >> 16);
}
DEVINL float bf2f(u16 s) {
  union { unsigned u; float f; } v; v.u = ((unsigned)s) << 16;
  return v.f;
}
DEVINL bf16x8 ld8(const u16* p) {
  return __builtin_bit_cast(bf16x8, *(const short8*)p);
}
DEVINL f32x4 mfma16(bf16x8 a, bf16x8 b, f32x4 c) {
  return __builtin_amdgcn_mfma_f32_16x16x32_bf16(a, b, c, 0, 0, 0);
}
DEVINL void async_cp16(const u16* gp, u16* lp) {
  __builtin_amdgcn_global_load_lds(
      (const __attribute__((address_space(1))) void*)gp,
      (__attribute__((address_space(3))) void*)lp, 16, 0, 0);
}

// ---------------- dtype casts ----------------
__global__ __launch_bounds__(256) void k_cast_x(const float* __restrict__ in,
                                                u16* __restrict__ out) {
  long i = (long)(blockIdx.x * 256 + threadIdx.x) * 4;
  float4 v = *(const float4*)(in + i);
  u16x4 o; o.x = f2bf(v.x); o.y = f2bf(v.y); o.z = f2bf(v.z); o.w = f2bf(v.w);
  *(u16x4*)(out + i) = o;
}
__global__ __launch_bounds__(256) void k_cast_w(const int* __restrict__ in,
                                                u16* __restrict__ out) {
  long i = (long)(blockIdx.x * 256 + threadIdx.x) * 4;
  int4 v = *(const int4*)(in + i);
  u16x4 o; o.x = f2bf((float)v.x); o.y = f2bf((float)v.y);
  o.z = f2bf((float)v.z); o.w = f2bf((float)v.w);
  *(u16x4*)(out + i) = o;
}

// ---------------- GEMM: C[m,n] = (sum_k A[m,k]*Bt[n,k]) * scale[n] ----------
template<bool OUT_BF16>
__global__ __launch_bounds__(256) void k_gemm_bt(
    const u16* __restrict__ A, const u16* __restrict__ Bt,
    const float* __restrict__ scale, void* __restrict__ Cv,
    int N, long K) {
  __shared__ u16 As[128 * 32];
  __shared__ u16 Bs[128 * 32];
  const int tid  = threadIdx.x;
  const int wave = tid >> 6;
  const int lane = tid & 63;
  const int l15  = lane & 15;
  const int quad = lane >> 4;
  const int wm = (wave & 1) * 64;
  const int wn = (wave >> 1) * 64;
  const long bm = (long)blockIdx.y * 128;
  const long bn = (long)blockIdx.x * 128;

  f32x4 acc[4][4] = {};

  const int srow = lane >> 2;
  const int scol = (lane & 3) * 8;

  for (long k0 = 0; k0 < K; k0 += 32) {
#pragma unroll
    for (int i = 0; i < 2; ++i) {
      const int j = wave * 2 + i;
      const int row = j * 16 + srow;
      async_cp16(A  + (bm + row) * K + k0 + scol, &As[j * 512]);
      async_cp16(Bt + (bn + row) * K + k0 + scol, &Bs[j * 512]);
    }
    __syncthreads();
    bf16x8 af[4], bfr[4];
#pragma unroll
    for (int mi = 0; mi < 4; ++mi)
      af[mi] = ld8(&As[(wm + mi * 16 + l15) * 32 + quad * 8]);
#pragma unroll
    for (int ni = 0; ni < 4; ++ni)
      bfr[ni] = ld8(&Bs[(wn + ni * 16 + l15) * 32 + quad * 8]);
#pragma unroll
    for (int mi = 0; mi < 4; ++mi)
#pragma unroll
      for (int ni = 0; ni < 4; ++ni)
        acc[mi][ni] = mfma16(af[mi], bfr[ni], acc[mi][ni]);
    __syncthreads();
  }
#pragma unroll
  for (int ni = 0; ni < 4; ++ni) {
    const long col = bn + wn + ni * 16 + l15;
    const float sc = scale[col];
#pragma unroll
    for (int mi = 0; mi < 4; ++mi) {
      const long row0 = bm + wm + mi * 16 + quad * 4;
#pragma unroll
      for (int r = 0; r < 4; ++r) {
        float v = acc[mi][ni][r] * sc;
        if constexpr (OUT_BF16) ((u16*)Cv)[(row0 + r) * (long)N + col] = f2bf(v);
        else                    ((float*)Cv)[(row0 + r) * (long)N + col] = v;
      }
    }
  }
}

// ---------------- l2norm(q,k); fold qk_gain^2*log2e/sqrt(HD) into q ---------
__global__ __launch_bounds__(256) void k_norm_qk(u16* __restrict__ qkv,
                                                 const float* __restrict__ qk_gain) {
  const int token = blockIdx.x;
  const int wave = threadIdx.x >> 6, lane = threadIdx.x & 63;
  const float g = qk_gain[0];
  const float qmul = g * g * 1.44269504f * 0.08838834764f;
  u16* rowp = qkv + (long)token * TC3;
#pragma unroll
  for (int s = 0; s < 8; ++s) {
    const int seg = wave * 8 + s;
    const int isK = seg >> 4;
    const int h = seg & 15;
    u16* ptr = rowp + isK * C_ + h * 128 + lane * 2;
    unsigned pv = *(const unsigned*)ptr;
    float a = bf2f((u16)(pv & 0xffffu));
    float bb = bf2f((u16)(pv >> 16));
    float ss = a * a + bb * bb;
#pragma unroll
    for (int m = 1; m <= 32; m <<= 1) ss += __shfl_xor(ss, m);
    float denom = fmaxf(sqrtf(ss), 1e-12f);
    float f = (isK ? 1.0f : qmul) / denom;
    u16 o0 = f2bf(a * f), o1 = f2bf(bb * f);
    *(unsigned*)ptr = (unsigned)o0 | ((unsigned)o1 << 16);
  }
}

// ---------------- V transpose: qkv V block -> Vt_g[bz][h][d][t] -------------
__global__ __launch_bounds__(256) void k_vt(const u16* __restrict__ qkv,
                                            u16* __restrict__ vt) {
  const int t0 = blockIdx.x * 64;
  const int h = blockIdx.y, bz = blockIdx.z;
  const int t = threadIdx.x & 63;
  const int d0 = threadIdx.x >> 6;         // 0..3
  const long tokbase = (long)bz * T_;
  const u16* src = qkv + (tokbase + t0 + t) * (long)TC3 + 2 * C_ + h * 128;
  u16* dst = vt + ((long)(bz * 16 + h) * 128) * (long)T_ + t0 + t;
#pragma unroll
  for (int dd = 0; dd < 32; ++dd) {
    const int d = dd * 4 + d0;
    dst[(long)d * T_] = src[d];
  }
}

// ---------------- flash attention (causal), S^T + async-staged tiles --------
__global__ __launch_bounds__(256) void k_attn(const u16* __restrict__ qkv,
                                              const u16* __restrict__ vtg,
                                              u16* __restrict__ y) {
  // qt pairing: co-resident blocks (y, y^8) get complementary strip lengths.
  const int qt = (blockIdx.y & 8) ? (31 - blockIdx.x) : blockIdx.x;
  const int h  = blockIdx.y;
  const int bz = blockIdx.z;
  const int tid = threadIdx.x, w = tid >> 6, lane = tid & 63;
  const int l15 = lane & 15, quad = lane >> 4;

  // Unpadded, XOR-swizzled in 16B chunks (global_load_lds-compatible).
  // Ks: 64 rows x 16 chunks; swizzle c^(r&15). Vt: 128 rows x 8 chunks;
  // swizzle c^(d&7). +640 u16 bump -> LDS 33.25KB -> exactly 4 blocks/CU,
  // aligning allocator occupancy target (128 regs) with actual need (~110).
  __shared__ u16 Ks[64 * 128];
  __shared__ u16 Vt[128 * 64 + 640];

  const long tokbase = (long)bz * T_;
  const int qbase = qt * 64 + w * 16;
  const u16* vbase = vtg + ((long)(bz * 16 + h) * 128) * (long)T_;
  const u16* kbase = qkv + tokbase * TC3 + C_ + h * 128;

  // Q fragments (frag map lane&15=query, quad*8+j=d) in registers
  bf16x8 qf[4];
  {
    const u16* qp = qkv + (tokbase + qbase + l15) * TC3 + h * 128 + quad * 8;
#pragma unroll
    for (int kc = 0; kc < 4; ++kc)
      qf[kc] = ld8(qp + kc * 32);
  }

  f32x4 o[8] = {};                         // O^T: (d = db*16+quad*4+r, m=l15)
  float mrow = -1e30f, lrow = 0.f;         // per-query scalars (lane-resident)

  for (int kt = 0; kt <= qt; ++kt) {
    const int ktb = kt * 64;
    // --- async staging: issue t=w*4+j covers chunks [t*64,(t+1)*64) ---
#pragma unroll
    for (int j = 0; j < 4; ++j) {
      const int t = w * 4 + j;
      const int p = t * 64 + lane;
      const int r  = p >> 4, ck = p & 15;          // K: row r, chunk ck
      async_cp16(kbase + (long)(ktb + r) * TC3 + ((ck ^ (r & 15)) * 8),
                 &Ks[t * 512]);
      const int d  = p >> 3, cv = p & 7;           // V: row d, chunk cv
      async_cp16(vbase + (long)d * T_ + ktb + ((cv ^ (d & 7)) * 8),
                 &Vt[t * 512]);
    }
    __syncthreads();   // compiler drains vmcnt before barrier

    const int nvalid = min(64, qbase + 16 - ktb);
    const int nkb = (nvalid + 15) >> 4;
    const int nkc = (nvalid + 31) >> 5;
    const bool diag = (kt == qt);

    // --- S^T = K·Q^T: C-layout (key=quad*4+r, query=l15) ---
    f32x4 sb[4] = {};                      // invalid kb stay 0 (PV-safe)
#pragma unroll
    for (int kb = 0; kb < 4; ++kb) {
      if (kb < nkb) {
        f32x4 acc = {0.f, 0.f, 0.f, 0.f};
#pragma unroll
        for (int kc = 0; kc < 4; ++kc) {
          bf16x8 kf = ld8(&Ks[(kb * 16 + l15) * 128 + (((kc * 4 + quad) ^ l15) * 8)]);
          acc = mfma16(kf, qf[kc], acc);
        }
        if (diag) {
          const int keyb = ktb + kb * 16 + quad * 4;
#pragma unroll
          for (int r = 0; r < 4; ++r)
            if (keyb + r > qbase + l15) acc[r] = -1e30f;
        }
        sb[kb] = acc;
      }
    }
    // --- online softmax: query on l15, reduce over regs + 2 shuffles ---
    float mx = -1e30f;
#pragma unroll
    for (int kb = 0; kb < 4; ++kb)
      if (kb < nkb)
#pragma unroll
        for (int r = 0; r < 4; ++r) mx = fmaxf(mx, sb[kb][r]);
    mx = fmaxf(mx, __shfl_xor(mx, 16));
    mx = fmaxf(mx, __shfl_xor(mx, 32));
    const float mnew = fmaxf(mrow, mx);
    const float alpha = __builtin_amdgcn_exp2f(mrow - mnew);
    mrow = mnew;
    float rs = 0.f;
#pragma unroll
    for (int kb = 0; kb < 4; ++kb)
      if (kb < nkb)
#pragma unroll
        for (int r = 0; r < 4; ++r) {
          float p = __builtin_amdgcn_exp2f(sb[kb][r] - mnew);
          sb[kb][r] = p;
          rs += p;
        }
    rs += __shfl_xor(rs, 16);
    rs += __shfl_xor(rs, 32);
    lrow = lrow * alpha + rs;
#pragma unroll
    for (int db = 0; db < 8; ++db)
#pragma unroll
      for (int r = 0; r < 4; ++r) o[db][r] *= alpha;

    // --- P^T C-frags -> B-frag via quad exchange; O^T += V^T P^T ---
#pragma unroll
    for (int kc2 = 0; kc2 < 2; ++kc2) {
      if (kc2 < nkc) {
        f32x4 e0 = sb[kc2 * 2], e1 = sb[kc2 * 2 + 1];
        f32x4 Y, Z;
#pragma unroll
        for (int i = 0; i < 4; ++i) {
          Y[i] = (quad & 2) ? e1[i] : e0[i];
          Z[i] = (quad & 2) ? e0[i] : e1[i];
        }
        f32x4 r16, r32, r48;
#pragma unroll
        for (int i = 0; i < 4; ++i) {
          r16[i] = __shfl_xor(Y[i], 16);
          r32[i] = __shfl_xor(Z[i], 32);
          r48[i] = __shfl_xor(Z[i], 48);
        }
        // lo: source quad (q&1)*2, regs j=0..3 ; hi: source quad (q&1)*2+1
        f32x4 lo, hi;
#pragma unroll
        for (int i = 0; i < 4; ++i) {
          lo[i] = (quad == 0) ? Y[i] : (quad == 1) ? r48[i] : (quad == 2) ? r32[i] : r16[i];
          hi[i] = (quad == 0) ? r16[i] : (quad == 1) ? r32[i] : (quad == 2) ? r48[i] : Y[i];
        }
        bf16x8 pb;
#pragma unroll
        for (int i = 0; i < 4; ++i) {
          pb[i]     = (__bf16)lo[i];
          pb[i + 4] = (__bf16)hi[i];
        }
#pragma unroll
        for (int db = 0; db < 8; ++db) {
          bf16x8 vf = ld8(&Vt[(db * 16 + l15) * 64 + (((kc2 * 4 + quad) ^ (l15 & 7)) * 8)]);
          o[db] = mfma16(vf, pb, o[db]);
        }
      }
    }
    __syncthreads();
  }
  // --- epilogue: O^T lane holds (d=db*16+quad*4+r, m=l15); y[m][d] ---
  const float inv_l = 1.0f / lrow;
  u16* yp = y + (tokbase + qbase + l15) * (long)C_ + h * 128 + quad * 4;
#pragma unroll
  for (int db = 0; db < 8; ++db) {
    u16x4 pk;
#pragma unroll
    for (int r = 0; r < 4; ++r) pk[r] = f2bf(o[db][r] * inv_l);
    *(u16x4*)(yp + db * 16) = pk;
  }
}

// ---------------------------------------------------------------------------
extern "C" void kernel_launch(void* const* d_in, const int* in_sizes, int n_in,
                              void* d_out, int out_size, void* d_ws, size_t ws_size,
                              hipStream_t stream) {
  const float* x    = (const float*)d_in[0];
  const int*   aw   = (const int*)d_in[1];
  const float* asc  = (const float*)d_in[2];
  const int*   pw   = (const int*)d_in[3];
  const float* psc  = (const float*)d_in[4];
  const float* gain = (const float*)d_in[5];

  char* ws = (char*)d_ws;
  u16* xb  = (u16*)(ws);                         // 16.78 MB (reused as Vt_g)
  u16* wab = (u16*)(ws + 16777216UL);
  u16* wpb = (u16*)(ws + 41943040UL);
  u16* qkv = (u16*)(ws + 50331648UL);
  u16* yb  = (u16*)(ws + 100663296UL);
  u16* vtg = xb;                                 // x_bf16 dead after QKV GEMM

  k_cast_x<<<8192, 256, 0, stream>>>(x, xb);
  k_cast_w<<<12288, 256, 0, stream>>>(aw, wab);
  k_cast_w<<<4096, 256, 0, stream>>>(pw, wpb);
  k_gemm_bt<true><<<dim3(48, 32), 256, 0, stream>>>(xb, wab, asc, qkv, TC3, (long)C_);
  k_norm_qk<<<4096, 256, 0, stream>>>(qkv, gain);
  k_vt<<<dim3(32, 16, 2), 256, 0, stream>>>(qkv, vtg);
  k_attn<<<dim3(32, 16, 2), 256, 0, stream>>>(qkv, vtg, yb);
  k_gemm_bt<false><<<dim3(16, 32), 256, 0, stream>>>(yb, wpb, psc, (float*)d_out, C_, (long)C_);
}

// Round 7
// 520.615 us; speedup vs baseline: 1.2387x; 1.0659x over previous
//
#include <hip/hip_runtime.h>

// ---------------------------------------------------------------------------
// QKGainAttention on MI355X (gfx950), round 7.
// R6 postmortem: spill fixed, conflicts 0, but attn stuck at 208us -- the
// stage->drain->compute->barrier chain serializes (all pipes <30% busy).
// R7: (1) bounded-score softmax: |s|<=g^2*1.4427/sqrt(128)~0.13 (q,k are
// l2-normed), so fix m=0 -> no running max/alpha/o-rescale, lrow is a
// per-lane partial reduced once at epilogue; causal mask subsumes tile
// masking -> branch-free inner loop. (2) double-buffered async staging,
// ONE barrier per tile: prefetch kt+1 issued before compute(kt), so the
// compiler's vmcnt(0)-before-barrier drain lands after compute (latency
// hidden). LDS 64KB -> 2 blocks/CU -> 256-reg budget (spill-proof).
// ---------------------------------------------------------------------------

#define DEVINL __device__ __forceinline__

typedef unsigned short u16;
typedef __bf16 bf16x8 __attribute__((ext_vector_type(8)));
typedef float  f32x4  __attribute__((ext_vector_type(4)));
typedef short  short8 __attribute__((ext_vector_type(8)));
typedef u16    u16x4  __attribute__((ext_vector_type(4)));

static constexpr int T_  = 2048;
static constexpr int C_  = 2048;
static constexpr int TC3 = 6144;   // 3*C

DEVINL u16 f2bf(float f) {
  union { float f; unsigned u; } v; v.f = f;
  unsigned r = v.u + 0x7FFFu + ((v.u >> 16) & 1u);   // RNE
  return (u16)(r >> 16);
}
DEVINL float bf2f(u16 s) {
  union { unsigned u; float f; } v; v.u = ((unsigned)s) << 16;
  return v.f;
}
DEVINL bf16x8 ld8(const u16* p) {
  return __builtin_bit_cast(bf16x8, *(const short8*)p);
}
DEVINL f32x4 mfma16(bf16x8 a, bf16x8 b, f32x4 c) {
  return __builtin_amdgcn_mfma_f32_16x16x32_bf16(a, b, c, 0, 0, 0);
}
DEVINL void async_cp16(const u16* gp, u16* lp) {
  __builtin_amdgcn_global_load_lds(
      (const __attribute__((address_space(1))) void*)gp,
      (__attribute__((address_space(3))) void*)lp, 16, 0, 0);
}

// ---------------- dtype casts ----------------
__global__ __launch_bounds__(256) void k_cast_x(const float* __restrict__ in,
                                                u16* __restrict__ out) {
  long i = (long)(blockIdx.x * 256 + threadIdx.x) * 4;
  float4 v = *(const float4*)(in + i);
  u16x4 o; o.x = f2bf(v.x); o.y = f2bf(v.y); o.z = f2bf(v.z); o.w = f2bf(v.w);
  *(u16x4*)(out + i) = o;
}
__global__ __launch_bounds__(256) void k_cast_w(const int* __restrict__ in,
                                                u16* __restrict__ out) {
  long i = (long)(blockIdx.x * 256 + threadIdx.x) * 4;
  int4 v = *(const int4*)(in + i);
  u16x4 o; o.x = f2bf((float)v.x); o.y = f2bf((float)v.y);
  o.z = f2bf((float)v.z); o.w = f2bf((float)v.w);
  *(u16x4*)(out + i) = o;
}

// ---------------- GEMM: C[m,n] = (sum_k A[m,k]*Bt[n,k]) * scale[n] ----------
template<bool OUT_BF16>
__global__ __launch_bounds__(256) void k_gemm_bt(
    const u16* __restrict__ A, const u16* __restrict__ Bt,
    const float* __restrict__ scale, void* __restrict__ Cv,
    int N, long K) {
  __shared__ u16 As[128 * 32];
  __shared__ u16 Bs[128 * 32];
  const int tid  = threadIdx.x;
  const int wave = tid >> 6;
  const int lane = tid & 63;
  const int l15  = lane & 15;
  const int quad = lane >> 4;
  const int wm = (wave & 1) * 64;
  const int wn = (wave >> 1) * 64;
  const long bm = (long)blockIdx.y * 128;
  const long bn = (long)blockIdx.x * 128;

  f32x4 acc[4][4] = {};

  const int srow = lane >> 2;
  const int scol = (lane & 3) * 8;

  for (long k0 = 0; k0 < K; k0 += 32) {
#pragma unroll
    for (int i = 0; i < 2; ++i) {
      const int j = wave * 2 + i;
      const int row = j * 16 + srow;
      async_cp16(A  + (bm + row) * K + k0 + scol, &As[j * 512]);
      async_cp16(Bt + (bn + row) * K + k0 + scol, &Bs[j * 512]);
    }
    __syncthreads();
    bf16x8 af[4], bfr[4];
#pragma unroll
    for (int mi = 0; mi < 4; ++mi)
      af[mi] = ld8(&As[(wm + mi * 16 + l15) * 32 + quad * 8]);
#pragma unroll
    for (int ni = 0; ni < 4; ++ni)
      bfr[ni] = ld8(&Bs[(wn + ni * 16 + l15) * 32 + quad * 8]);
#pragma unroll
    for (int mi = 0; mi < 4; ++mi)
#pragma unroll
      for (int ni = 0; ni < 4; ++ni)
        acc[mi][ni] = mfma16(af[mi], bfr[ni], acc[mi][ni]);
    __syncthreads();
  }
#pragma unroll
  for (int ni = 0; ni < 4; ++ni) {
    const long col = bn + wn + ni * 16 + l15;
    const float sc = scale[col];
#pragma unroll
    for (int mi = 0; mi < 4; ++mi) {
      const long row0 = bm + wm + mi * 16 + quad * 4;
#pragma unroll
      for (int r = 0; r < 4; ++r) {
        float v = acc[mi][ni][r] * sc;
        if constexpr (OUT_BF16) ((u16*)Cv)[(row0 + r) * (long)N + col] = f2bf(v);
        else                    ((float*)Cv)[(row0 + r) * (long)N + col] = v;
      }
    }
  }
}

// ---------------- l2norm(q,k); fold qk_gain^2*log2e/sqrt(HD) into q ---------
__global__ __launch_bounds__(256) void k_norm_qk(u16* __restrict__ qkv,
                                                 const float* __restrict__ qk_gain) {
  const int token = blockIdx.x;
  const int wave = threadIdx.x >> 6, lane = threadIdx.x & 63;
  const float g = qk_gain[0];
  const float qmul = g * g * 1.44269504f * 0.08838834764f;
  u16* rowp = qkv + (long)token * TC3;
#pragma unroll
  for (int s = 0; s < 8; ++s) {
    const int seg = wave * 8 + s;
    const int isK = seg >> 4;
    const int h = seg & 15;
    u16* ptr = rowp + isK * C_ + h * 128 + lane * 2;
    unsigned pv = *(const unsigned*)ptr;
    float a = bf2f((u16)(pv & 0xffffu));
    float bb = bf2f((u16)(pv >> 16));
    float ss = a * a + bb * bb;
#pragma unroll
    for (int m = 1; m <= 32; m <<= 1) ss += __shfl_xor(ss, m);
    float denom = fmaxf(sqrtf(ss), 1e-12f);
    float f = (isK ? 1.0f : qmul) / denom;
    u16 o0 = f2bf(a * f), o1 = f2bf(bb * f);
    *(unsigned*)ptr = (unsigned)o0 | ((unsigned)o1 << 16);
  }
}

// ---------------- V transpose: qkv V block -> Vt_g[bz][h][d][t] -------------
__global__ __launch_bounds__(256) void k_vt(const u16* __restrict__ qkv,
                                            u16* __restrict__ vt) {
  const int t0 = blockIdx.x * 64;
  const int h = blockIdx.y, bz = blockIdx.z;
  const int t = threadIdx.x & 63;
  const int d0 = threadIdx.x >> 6;         // 0..3
  const long tokbase = (long)bz * T_;
  const u16* src = qkv + (tokbase + t0 + t) * (long)TC3 + 2 * C_ + h * 128;
  u16* dst = vt + ((long)(bz * 16 + h) * 128) * (long)T_ + t0 + t;
#pragma unroll
  for (int dd = 0; dd < 32; ++dd) {
    const int d = dd * 4 + d0;
    dst[(long)d * T_] = src[d];
  }
}

// ---------------- flash attention (causal), m=0 softmax, dbuf staging -------
__global__ __launch_bounds__(256) void k_attn(const u16* __restrict__ qkv,
                                              const u16* __restrict__ vtg,
                                              u16* __restrict__ y) {
  // qt pairing: co-resident blocks (y, y^8) get complementary strip lengths.
  const int qt = (blockIdx.y & 8) ? (31 - blockIdx.x) : blockIdx.x;
  const int h  = blockIdx.y;
  const int bz = blockIdx.z;
  const int tid = threadIdx.x, w = tid >> 6, lane = tid & 63;
  const int l15 = lane & 15, quad = lane >> 4;

  // Double-buffered, unpadded, XOR-chunk-swizzled (global_load_lds dest is
  // wave-uniform base + lane*16). 64KB total -> 2 blocks/CU -> 256-reg budget.
  __shared__ u16 Ks[2][64 * 128];
  __shared__ u16 Vt[2][128 * 64];

  const long tokbase = (long)bz * T_;
  const int qbase = qt * 64 + w * 16;
  const u16* vbase = vtg + ((long)(bz * 16 + h) * 128) * (long)T_;
  const u16* kbase = qkv + tokbase * TC3 + C_ + h * 128;

  // Q fragments (frag map lane&15=query, quad*8+j=d) in registers
  bf16x8 qf[4];
  {
    const u16* qp = qkv + (tokbase + qbase + l15) * TC3 + h * 128 + quad * 8;
#pragma unroll
    for (int kc = 0; kc < 4; ++kc)
      qf[kc] = ld8(qp + kc * 32);
  }

  f32x4 o[8] = {};                         // O^T: (d = db*16+quad*4+r, m=l15)
  float lrow = 0.f;                        // per-lane PARTIAL sum (m == 0)

  auto stage = [&](int ktb, int b) {
#pragma unroll
    for (int j = 0; j < 4; ++j) {
      const int t = w * 4 + j;
      const int p = t * 64 + lane;
      const int r  = p >> 4, ck = p & 15;          // K: row r, chunk ck
      async_cp16(kbase + (long)(ktb + r) * TC3 + ((ck ^ (r & 15)) * 8),
                 &Ks[b][t * 512]);
      const int d  = p >> 3, cv = p & 7;           // V: row d, chunk cv
      async_cp16(vbase + (long)d * T_ + ktb + ((cv ^ (d & 7)) * 8),
                 &Vt[b][t * 512]);
    }
  };

  stage(0, 0);
  __syncthreads();                         // drain tile-0 staging
  int b = 0;

  for (int kt = 0; kt <= qt; ++kt) {
    const int ktb = kt * 64;
    // --- prefetch next tile into the other buffer (drained at the barrier
    //     AFTER compute -> latency overlapped with compute) ---
    if (kt < qt) stage(ktb + 64, b ^ 1);

    const bool diag = (kt == qt);

    // --- S^T = K·Q^T: C-layout (key=quad*4+r, query=l15) ---
    f32x4 sb[4];
#pragma unroll
    for (int kb = 0; kb < 4; ++kb) {
      f32x4 acc = {0.f, 0.f, 0.f, 0.f};
#pragma unroll
      for (int kc = 0; kc < 4; ++kc) {
        bf16x8 kf = ld8(&Ks[b][(kb * 16 + l15) * 128 + (((kc * 4 + quad) ^ l15) * 8)]);
        acc = mfma16(kf, qf[kc], acc);
      }
      if (diag) {
        const int keyb = ktb + kb * 16 + quad * 4;
#pragma unroll
        for (int r = 0; r < 4; ++r)
          if (keyb + r > qbase + l15) acc[r] = -1e30f;   // exp2 -> 0
      }
      sb[kb] = acc;
    }
    // --- m=0 softmax: P = exp2(s) directly (|s| bounded ~0.13); lrow is a
    //     per-lane partial, reduced once in the epilogue ---
#pragma unroll
    for (int kb = 0; kb < 4; ++kb)
#pragma unroll
      for (int r = 0; r < 4; ++r) {
        float p = __builtin_amdgcn_exp2f(sb[kb][r]);
        sb[kb][r] = p;
        lrow += p;
      }

    // --- P^T C-frags -> B-frag via quad exchange; O^T += V^T P^T ---
#pragma unroll
    for (int kc2 = 0; kc2 < 2; ++kc2) {
      f32x4 e0 = sb[kc2 * 2], e1 = sb[kc2 * 2 + 1];
      f32x4 Y, Z;
#pragma unroll
      for (int i = 0; i < 4; ++i) {
        Y[i] = (quad & 2) ? e1[i] : e0[i];
        Z[i] = (quad & 2) ? e0[i] : e1[i];
      }
      f32x4 r16, r32, r48;
#pragma unroll
      for (int i = 0; i < 4; ++i) {
        r16[i] = __shfl_xor(Y[i], 16);
        r32[i] = __shfl_xor(Z[i], 32);
        r48[i] = __shfl_xor(Z[i], 48);
      }
      f32x4 lo, hi;
#pragma unroll
      for (int i = 0; i < 4; ++i) {
        lo[i] = (quad == 0) ? Y[i] : (quad == 1) ? r48[i] : (quad == 2) ? r32[i] : r16[i];
        hi[i] = (quad == 0) ? r16[i] : (quad == 1) ? r32[i] : (quad == 2) ? r48[i] : Y[i];
      }
      bf16x8 pb;
#pragma unroll
      for (int i = 0; i < 4; ++i) {
        pb[i]     = (__bf16)lo[i];
        pb[i + 4] = (__bf16)hi[i];
      }
#pragma unroll
      for (int db = 0; db < 8; ++db) {
        bf16x8 vf = ld8(&Vt[b][(db * 16 + l15) * 64 + (((kc2 * 4 + quad) ^ (l15 & 7)) * 8)]);
        o[db] = mfma16(vf, pb, o[db]);
      }
    }
    if (kt < qt) __syncthreads();          // drains prefetch + guards buffers
    b ^= 1;
  }
  // --- epilogue: reduce lrow across quads (2 shuffles), write O^T ---
  lrow += __shfl_xor(lrow, 16);
  lrow += __shfl_xor(lrow, 32);
  const float inv_l = 1.0f / lrow;
  u16* yp = y + (tokbase + qbase + l15) * (long)C_ + h * 128 + quad * 4;
#pragma unroll
  for (int db = 0; db < 8; ++db) {
    u16x4 pk;
#pragma unroll
    for (int r = 0; r < 4; ++r) pk[r] = f2bf(o[db][r] * inv_l);
    *(u16x4*)(yp + db * 16) = pk;
  }
}

// ---------------------------------------------------------------------------
extern "C" void kernel_launch(void* const* d_in, const int* in_sizes, int n_in,
                              void* d_out, int out_size, void* d_ws, size_t ws_size,
                              hipStream_t stream) {
  const float* x    = (const float*)d_in[0];
  const int*   aw   = (const int*)d_in[1];
  const float* asc  = (const float*)d_in[2];
  const int*   pw   = (const int*)d_in[3];
  const float* psc  = (const float*)d_in[4];
  const float* gain = (const float*)d_in[5];

  char* ws = (char*)d_ws;
  u16* xb  = (u16*)(ws);                         // 16.78 MB (reused as Vt_g)
  u16* wab = (u16*)(ws + 16777216UL);
  u16* wpb = (u16*)(ws + 41943040UL);
  u16* qkv = (u16*)(ws + 50331648UL);
  u16* yb  = (u16*)(ws + 100663296UL);
  u16* vtg = xb;                                 // x_bf16 dead after QKV GEMM

  k_cast_x<<<8192, 256, 0, stream>>>(x, xb);
  k_cast_w<<<12288, 256, 0, stream>>>(aw, wab);
  k_cast_w<<<4096, 256, 0, stream>>>(pw, wpb);
  k_gemm_bt<true><<<dim3(48, 32), 256, 0, stream>>>(xb, wab, asc, qkv, TC3, (long)C_);
  k_norm_qk<<<4096, 256, 0, stream>>>(qkv, gain);
  k_vt<<<dim3(32, 16, 2), 256, 0, stream>>>(qkv, vtg);
  k_attn<<<dim3(32, 16, 2), 256, 0, stream>>>(qkv, vtg, yb);
  k_gemm_bt<false><<<dim3(16, 32), 256, 0, stream>>>(yb, wpb, psc, (float*)d_out, C_, (long)C_);
}